// Round 7
// baseline (1479.050 us; speedup 1.0000x reference)
//
#include <hip/hip_runtime.h>
#include <hip/hip_bf16.h>

typedef float f2 __attribute__((ext_vector_type(2)));
typedef float f4 __attribute__((ext_vector_type(4)));
typedef _Float16 h2 __attribute__((ext_vector_type(2)));
typedef unsigned u4 __attribute__((ext_vector_type(4)));

#define BB 64
#define TT 2048
#define II 64
#define HH 128
#define OO 64

// 2*log2(e): folded into W_hh and xp so tanh needs only exp2 (v_exp_f32).
#define SCALE_C 2.885390081777927f

// ---------- f16 pair helpers ----------
__device__ __forceinline__ unsigned pack_h16(float a, float b) {
    h2 p; p.x = (_Float16)a; p.y = (_Float16)b;   // v_cvt_f16_f32 is RNE
    return __builtin_bit_cast(unsigned, p);
}
__device__ __forceinline__ float h16_lo(unsigned u) {
    h2 p = __builtin_bit_cast(h2, u); return (float)p.x;
}
__device__ __forceinline__ float h16_hi(unsigned u) {
    h2 p = __builtin_bit_cast(h2, u); return (float)p.y;
}
// Guaranteed single-instruction f16 dot2 with f32 accumulate.
__device__ __forceinline__ float dot2asm(unsigned a, unsigned b, float c) {
    float d;
    asm("v_dot2_f32_f16 %0, %1, %2, %3" : "=v"(d) : "v"(a), "v"(b), "v"(c));
    return d;
}
// Raw exp2; s_nop covers the VALU-trans hazard (inline asm bypasses the
// compiler's hazard recognizer).
__device__ __forceinline__ float exp2asm(float x) {
    float r;
    asm("v_exp_f32 %0, %1\n\ts_nop 1" : "=v"(r) : "v"(x));
    return r;
}

// =====================================================================
// Kernel 1: xp[d][b][t][pair] (f16 pairs) = C*(x[b,t,:]·Wih_d[h,:] + bias)
// =====================================================================
__global__ __launch_bounds__(256, 1)
void xp_kernel(const float* __restrict__ x,
               const float* __restrict__ Wih_f, const float* __restrict__ bih_f,
               const float* __restrict__ bhh_f,
               const float* __restrict__ Wih_b, const float* __restrict__ bih_b,
               const float* __restrict__ bhh_b,
               unsigned* __restrict__ xp)
{
    const int blk = blockIdx.x;
    const int tt = blk & 7;
    const int b  = (blk >> 3) & 63;
    const int d  = blk >> 9;
    const float* __restrict__ Wih = d ? Wih_b : Wih_f;
    const float* __restrict__ bih = d ? bih_b : bih_f;
    const float* __restrict__ bhh = d ? bhh_b : bhh_f;

    const int tid = threadIdx.x;
    const int w   = tid >> 6;
    const int l   = tid & 63;

    __shared__ float xs[256 * II];   // 64 KiB

    const float* xsrc = x + ((size_t)b * TT + (size_t)tt * 256) * II;
    for (int i = tid; i < 256 * II / 4; i += 256)
        ((f4*)xs)[i] = ((const f4*)xsrc)[i];

    f2 w0[32], w1[32];
    {
        const f4* s0 = (const f4*)(Wih + (size_t)(2 * l) * II);
        const f4* s1 = (const f4*)(Wih + (size_t)(2 * l + 1) * II);
        #pragma unroll
        for (int m = 0; m < 16; ++m) {
            f4 v0 = s0[m], v1 = s1[m];
            w0[2 * m] = (f2){v0.x, v0.y}; w0[2 * m + 1] = (f2){v0.z, v0.w};
            w1[2 * m] = (f2){v1.x, v1.y}; w1[2 * m + 1] = (f2){v1.z, v1.w};
        }
    }
    const float bias0 = bih[2 * l]     + bhh[2 * l];
    const float bias1 = bih[2 * l + 1] + bhh[2 * l + 1];
    __syncthreads();

    unsigned* xpd = xp + ((size_t)(d * BB + b) * TT + (size_t)tt * 256) * (HH / 2);
    for (int ti = 0; ti < 64; ++ti) {
        const int t_loc = w * 64 + ti;
        const f4* xr = (const f4*)(xs + t_loc * II);
        f2 a0 = (f2){0, 0}, a0b = (f2){0, 0}, a1 = (f2){0, 0}, a1b = (f2){0, 0};
        #pragma unroll
        for (int m = 0; m < 16; ++m) {
            f4 v = xr[m];
            f2 lo = (f2){v.x, v.y}, hi = (f2){v.z, v.w};
            a0  += w0[2 * m] * lo;  a0b += w0[2 * m + 1] * hi;
            a1  += w1[2 * m] * lo;  a1b += w1[2 * m + 1] * hi;
        }
        float z0 = (a0.x + a0.y + a0b.x + a0b.y + bias0) * SCALE_C;
        float z1 = (a1.x + a1.y + a1b.x + a1b.y + bias1) * SCALE_C;
        xpd[(size_t)t_loc * (HH / 2) + l] = pack_h16(z0, z1);
    }
}

// =====================================================================
// Kernel 2: serial recurrence v4 — ONE WAVE per (b,d), no barriers.
//   * Weights f16-packed in `unsigned` regs, PINNED via empty asm so the
//     scheduler cannot rematerialize them into the loop (round 4/5/6
//     failure mode: VGPR_Count stuck at 132/144 with in-loop reloads).
//   * v_dot2_f32_f16 via asm (no silent scalar fallback).
//   * W and xp pre-scaled by 2*log2(e): tanh = 1 - 2/(exp2(z')+1).
// =====================================================================
__global__ __launch_bounds__(64, 1)
void rnn_serial4(const float* __restrict__ Whh_f, const float* __restrict__ Whh_b,
                 const unsigned* __restrict__ xp, unsigned* __restrict__ y)
{
    const int l = threadIdx.x;          // lane: owns rows 2l, 2l+1
    const int b = blockIdx.x & 63;
    const int d = blockIdx.x >> 6;
    const float* __restrict__ Whh = d ? Whh_b : Whh_f;

    __shared__ __align__(16) unsigned hb[2][HH / 2];  // f16 pairs, 256 B/buf

    // rows 2l, 2l+1 of Whh, scaled by C, f16-packed -> 128 VGPRs
    unsigned wu0[64], wu1[64];
    {
        const f4* s0 = (const f4*)(Whh + (size_t)(2 * l) * HH);
        const f4* s1 = (const f4*)(Whh + (size_t)(2 * l + 1) * HH);
        #pragma unroll
        for (int m = 0; m < 32; ++m) {
            f4 v0 = s0[m], v1 = s1[m];
            wu0[2 * m]     = pack_h16(v0.x * SCALE_C, v0.y * SCALE_C);
            wu0[2 * m + 1] = pack_h16(v0.z * SCALE_C, v0.w * SCALE_C);
            wu1[2 * m]     = pack_h16(v1.x * SCALE_C, v1.y * SCALE_C);
            wu1[2 * m + 1] = pack_h16(v1.z * SCALE_C, v1.w * SCALE_C);
        }
    }
    // Pin: asm-defined values cannot be rematerialized; forces residency.
    #pragma unroll
    for (int i = 0; i < 64; ++i) {
        asm volatile("" : "+v"(wu0[i]));
        asm volatile("" : "+v"(wu1[i]));
    }

    hb[0][l] = 0u;   // h0 = 0

    const size_t base_pair = (size_t)(d * BB + b) * TT * (HH / 2);
    const unsigned* xpl = xp + base_pair + l;
    unsigned*       yl  = y  + base_pair + l;

    const int t0 = d ? (TT - 1) : 0;
    const int dt = d ? -1 : 1;

    unsigned xc = xpl[(size_t)t0 * (HH / 2)];
    unsigned xn = xpl[(size_t)(t0 + dt) * (HH / 2)];

    #pragma unroll 2
    for (int s = 0; s < TT; ++s) {
        const int cur = s & 1, nxt = cur ^ 1;

        // prefetch xp for s+2 — never waited this iteration
        unsigned xf = 0;
        if (s + 2 < TT) xf = xpl[(size_t)(t0 + dt * (s + 2)) * (HH / 2)];

        // z' = C*(Whh·h + xp): 16 uniform b128 reads, 128 dot2, 8 chains
        const u4* hr = (const u4*)hb[cur];
        float a00 = h16_lo(xc), a01 = 0, a02 = 0, a03 = 0;
        float a10 = h16_hi(xc), a11 = 0, a12 = 0, a13 = 0;
        #pragma unroll
        for (int m = 0; m < 16; ++m) {
            u4 v = hr[m];
            a00 = dot2asm(wu0[4 * m],     v.x, a00);
            a01 = dot2asm(wu0[4 * m + 1], v.y, a01);
            a02 = dot2asm(wu0[4 * m + 2], v.z, a02);
            a03 = dot2asm(wu0[4 * m + 3], v.w, a03);
            a10 = dot2asm(wu1[4 * m],     v.x, a10);
            a11 = dot2asm(wu1[4 * m + 1], v.y, a11);
            a12 = dot2asm(wu1[4 * m + 2], v.z, a12);
            a13 = dot2asm(wu1[4 * m + 3], v.w, a13);
        }
        float z0 = (a00 + a01) + (a02 + a03);
        float z1 = (a10 + a11) + (a12 + a13);

        // tanh(z) = 1 - 2/(2^{z'}+1), inf-safe
        float e0 = exp2asm(z0);
        float e1 = exp2asm(z1);
        float h0 = 1.f - __fdividef(2.f, e0 + 1.f);
        float h1 = 1.f - __fdividef(2.f, e1 + 1.f);

        const unsigned hp = pack_h16(h0, h1);
        hb[nxt][l] = hp;                              // DS in-order: no wait needed
        yl[(size_t)(t0 + dt * s) * (HH / 2)] = hp;    // streamed, never waited

        xc = xn; xn = xf;
    }
}

// =====================================================================
// Kernel 3: out[b][t][o] = Wout·[y_f;y_b] + bout  (f16 y, f32 math)
// =====================================================================
__global__ __launch_bounds__(256, 1)
void out_kernel(const unsigned* __restrict__ y, const float* __restrict__ Wout,
                const float* __restrict__ bout, float* __restrict__ out)
{
    const int blk = blockIdx.x;
    const int tt = blk & 31;
    const int b  = blk >> 5;
    const int tid = threadIdx.x;
    const int w = tid >> 6, l = tid & 63;

    __shared__ float ys[64][2 * HH];   // 64 KiB

    const unsigned* yf = y + ((size_t)(0 * BB + b) * TT + (size_t)tt * 64) * (HH / 2);
    const unsigned* yb = y + ((size_t)(1 * BB + b) * TT + (size_t)tt * 64) * (HH / 2);
    for (int i = tid; i < 64 * (HH / 2); i += 256) {
        const int t_loc = i >> 6, hp = i & 63;
        unsigned vf = yf[i], vb = yb[i];
        ys[t_loc][2 * hp]          = h16_lo(vf);
        ys[t_loc][2 * hp + 1]      = h16_hi(vf);
        ys[t_loc][HH + 2 * hp]     = h16_lo(vb);
        ys[t_loc][HH + 2 * hp + 1] = h16_hi(vb);
    }

    const int o  = 32 * (w & 1) + (l >> 1);
    const int ks = l & 1;
    f2 wv[64];
    {
        const f4* s = (const f4*)(Wout + (size_t)o * (2 * HH) + (size_t)ks * HH);
        #pragma unroll
        for (int m = 0; m < 32; ++m) {
            f4 v = s[m];
            wv[2 * m] = (f2){v.x, v.y}; wv[2 * m + 1] = (f2){v.z, v.w};
        }
    }
    const float bo = bout[o];
    __syncthreads();

    for (int i = 0; i < 32; ++i) {
        const int t_loc = 2 * i + (w >> 1);
        const f4* yr = (const f4*)(&ys[t_loc][ks * HH]);
        f2 acc = (f2){0, 0}, accb = (f2){0, 0};
        #pragma unroll
        for (int m = 0; m < 32; ++m) {
            f4 v = yr[m];
            acc  += wv[2 * m]     * (f2){v.x, v.y};
            accb += wv[2 * m + 1] * (f2){v.z, v.w};
        }
        float r = acc.x + acc.y + accb.x + accb.y;
        r += __shfl_xor(r, 1);
        if (ks == 0)
            out[((size_t)b * TT + (size_t)tt * 64 + t_loc) * OO + o] = r + bo;
    }
}

// =====================================================================
// Fallback (ws too small): known-good fused kernel from round 3 (1689 us).
// =====================================================================
__global__ __launch_bounds__(256, 1)
void birnn_fused(const float* __restrict__ x,
                 const float* __restrict__ Wih_f, const float* __restrict__ Whh_f,
                 const float* __restrict__ bih_f, const float* __restrict__ bhh_f,
                 const float* __restrict__ Wih_b, const float* __restrict__ Whh_b,
                 const float* __restrict__ bih_b, const float* __restrict__ bhh_b,
                 const float* __restrict__ Wout, const float* __restrict__ bout,
                 float* __restrict__ out)
{
    const int tid = threadIdx.x;
    const int b   = blockIdx.x & (BB - 1);
    const int d   = blockIdx.x >> 6;
    const float* __restrict__ Wih = d ? Wih_b : Wih_f;
    const float* __restrict__ Whh = d ? Whh_b : Whh_f;
    const float* __restrict__ bih = d ? bih_b : bih_f;
    const float* __restrict__ bhh = d ? bhh_b : bhh_f;
    const int j = tid >> 1, p = tid & 1, o = tid >> 2, os = tid & 3;
    __shared__ float hbuf[2][HH];
    __shared__ float xbuf[2][II];
    f2 whh[32], wih[16], wo[16];
    {
        const f4* s4 = (const f4*)(Whh + (size_t)j * HH + p * 64);
        #pragma unroll
        for (int m = 0; m < 16; ++m) { f4 v = s4[m]; whh[2*m]=(f2){v.x,v.y}; whh[2*m+1]=(f2){v.z,v.w}; }
    }
    {
        const f4* s4 = (const f4*)(Wih + (size_t)j * II + p * 32);
        #pragma unroll
        for (int m = 0; m < 8; ++m) { f4 v = s4[m]; wih[2*m]=(f2){v.x,v.y}; wih[2*m+1]=(f2){v.z,v.w}; }
    }
    {
        const f4* s4 = (const f4*)(Wout + (size_t)o * (2*HH) + d*HH + os*32);
        #pragma unroll
        for (int m = 0; m < 8; ++m) { f4 v = s4[m]; wo[2*m]=(f2){v.x,v.y}; wo[2*m+1]=(f2){v.z,v.w}; }
    }
    const float bj = bih[j] + bhh[j];
    const float bo = d ? 0.f : bout[o];
    const float* __restrict__ xb   = x   + (size_t)b * TT * II;
    float*       __restrict__ outb = out + (size_t)b * TT * OO;
    const int t0 = d ? (TT - 1) : 0;
    const int dt = d ? -1 : 1;
    float xpre = 0.f;
    if (tid < II) {
        xbuf[0][tid] = xb[(size_t)t0 * II + tid];
        xpre = xb[(size_t)(t0 + dt) * II + tid];
    }
    if (tid < HH) hbuf[0][tid] = 0.f;
    __syncthreads();
    #pragma unroll 2
    for (int s = 0; s < TT; ++s) {
        const int cur = s & 1, nxt = cur ^ 1;
        if (s > 0) {
            const f4* hv4 = (const f4*)(&hbuf[cur][os * 32]);
            f2 acc = (f2){0.f, 0.f};
            #pragma unroll
            for (int m = 0; m < 8; ++m) { f4 h4 = hv4[m]; acc += wo[2*m]*(f2){h4.x,h4.y}; acc += wo[2*m+1]*(f2){h4.z,h4.w}; }
            float v = acc.x + acc.y;
            v += __shfl_xor(v, 1); v += __shfl_xor(v, 2);
            if (os == 0) atomicAdd(&outb[(size_t)(t0 + dt*(s-1)) * OO + o], v + bo);
        }
        {
            const f4* hv4 = (const f4*)(&hbuf[cur][p * 64]);
            const f4* xv4 = (const f4*)(&xbuf[cur][p * 32]);
            f2 acc = (f2){0.f, 0.f};
            #pragma unroll
            for (int m = 0; m < 16; ++m) { f4 h4 = hv4[m]; acc += whh[2*m]*(f2){h4.x,h4.y}; acc += whh[2*m+1]*(f2){h4.z,h4.w}; }
            #pragma unroll
            for (int m = 0; m < 8; ++m) { f4 x4 = xv4[m]; acc += wih[2*m]*(f2){x4.x,x4.y}; acc += wih[2*m+1]*(f2){x4.z,x4.w}; }
            float z = acc.x + acc.y;
            z += __shfl_xor(z, 1);
            z += bj;
            float e = __expf(2.f * z);
            float h = 1.f - __fdividef(2.f, e + 1.f);
            if (p == 0) hbuf[nxt][j] = h;
        }
        if (tid < II) {
            xbuf[nxt][tid] = xpre;
            if (s + 2 < TT) xpre = xb[(size_t)(t0 + dt*(s+2)) * II + tid];
        }
        __syncthreads();
    }
    {
        const f4* hv4 = (const f4*)(&hbuf[TT & 1][os * 32]);
        f2 acc = (f2){0.f, 0.f};
        #pragma unroll
        for (int m = 0; m < 8; ++m) { f4 h4 = hv4[m]; acc += wo[2*m]*(f2){h4.x,h4.y}; acc += wo[2*m+1]*(f2){h4.z,h4.w}; }
        float v = acc.x + acc.y;
        v += __shfl_xor(v, 1); v += __shfl_xor(v, 2);
        if (os == 0) atomicAdd(&outb[(size_t)(t0 + dt*(TT-1)) * OO + o], v + bo);
    }
}

extern "C" void kernel_launch(void* const* d_in, const int* in_sizes, int n_in,
                              void* d_out, int out_size, void* d_ws, size_t ws_size,
                              hipStream_t stream) {
    const float* x     = (const float*)d_in[0];
    const float* Wih_f = (const float*)d_in[1];
    const float* Whh_f = (const float*)d_in[2];
    const float* bih_f = (const float*)d_in[3];
    const float* bhh_f = (const float*)d_in[4];
    const float* Wih_b = (const float*)d_in[5];
    const float* Whh_b = (const float*)d_in[6];
    const float* bih_b = (const float*)d_in[7];
    const float* bhh_b = (const float*)d_in[8];
    const float* Wout  = (const float*)d_in[9];
    const float* bout  = (const float*)d_in[10];
    float* out = (float*)d_out;

    const size_t xp_bytes = (size_t)2 * BB * TT * (HH / 2) * 4;  // 64 MiB (f16 pairs)
    const size_t y_bytes  = xp_bytes;                             // 64 MiB
    if (ws_size >= xp_bytes + y_bytes) {
        unsigned* xp_ws = (unsigned*)d_ws;
        unsigned* y_ws  = (unsigned*)((char*)d_ws + xp_bytes);
        xp_kernel<<<dim3(1024), dim3(256), 0, stream>>>(
            x, Wih_f, bih_f, bhh_f, Wih_b, bih_b, bhh_b, xp_ws);
        rnn_serial4<<<dim3(2 * BB), dim3(64), 0, stream>>>(
            Whh_f, Whh_b, xp_ws, y_ws);
        out_kernel<<<dim3(2048), dim3(256), 0, stream>>>(y_ws, Wout, bout, out);
    } else {
        hipMemsetAsync(d_out, 0, (size_t)out_size * sizeof(float), stream);
        birnn_fused<<<dim3(2 * BB), dim3(256), 0, stream>>>(
            x, Wih_f, Whh_f, bih_f, bhh_f,
            Wih_b, Whh_b, bih_b, bhh_b, Wout, bout, out);
    }
}

// Round 10
// 1163.517 us; speedup vs baseline: 1.2712x; 1.2712x over previous
//
#include <hip/hip_runtime.h>
#include <hip/hip_bf16.h>

typedef float f2 __attribute__((ext_vector_type(2)));
typedef float f4 __attribute__((ext_vector_type(4)));
typedef _Float16 h2 __attribute__((ext_vector_type(2)));
typedef unsigned u4 __attribute__((ext_vector_type(4)));

#define BB 64
#define TT 2048
#define II 64
#define HH 128
#define OO 64

// 2*log2(e): folded into W_hh and xp so tanh needs only exp2 (round 7 proven).
#define SCALE_C 2.885390081777927f

// ---------- f16 helpers (round 6/7 proven) ----------
__device__ __forceinline__ unsigned pack_h16(float a, float b) {
    h2 p; p.x = (_Float16)a; p.y = (_Float16)b;   // v_cvt_f16_f32 is RNE
    return __builtin_bit_cast(unsigned, p);
}
__device__ __forceinline__ float h16_lo(unsigned u) {
    h2 p = __builtin_bit_cast(h2, u); return (float)p.x;
}
__device__ __forceinline__ float h16_hi(unsigned u) {
    h2 p = __builtin_bit_cast(h2, u); return (float)p.y;
}
// Guaranteed single-instruction f16 dot2 with f32 accumulate (round 7 proven).
__device__ __forceinline__ float dot2asm(unsigned a, unsigned b, float c) {
    float d;
    asm("v_dot2_f32_f16 %0, %1, %2, %3" : "=v"(d) : "v"(a), "v"(b), "v"(c));
    return d;
}
// Raw exp2; s_nop covers the trans hazard (round 7 proven).
__device__ __forceinline__ float exp2asm(float x) {
    float r;
    asm("v_exp_f32 %0, %1\n\ts_nop 1" : "=v"(r) : "v"(x));
    return r;
}

// =====================================================================
// Kernel 1 (verbatim from round 7, PASSED): xp (f16 pairs) =
//   C*(x[b,t,:]·Wih_d[h,:] + bih + bhh)
// =====================================================================
__global__ __launch_bounds__(256, 1)
void xp_kernel(const float* __restrict__ x,
               const float* __restrict__ Wih_f, const float* __restrict__ bih_f,
               const float* __restrict__ bhh_f,
               const float* __restrict__ Wih_b, const float* __restrict__ bih_b,
               const float* __restrict__ bhh_b,
               unsigned* __restrict__ xp)
{
    const int blk = blockIdx.x;
    const int tt = blk & 7;
    const int b  = (blk >> 3) & 63;
    const int d  = blk >> 9;
    const float* __restrict__ Wih = d ? Wih_b : Wih_f;
    const float* __restrict__ bih = d ? bih_b : bih_f;
    const float* __restrict__ bhh = d ? bhh_b : bhh_f;

    const int tid = threadIdx.x;
    const int w   = tid >> 6;
    const int l   = tid & 63;

    __shared__ float xs[256 * II];   // 64 KiB

    const float* xsrc = x + ((size_t)b * TT + (size_t)tt * 256) * II;
    for (int i = tid; i < 256 * II / 4; i += 256)
        ((f4*)xs)[i] = ((const f4*)xsrc)[i];

    f2 w0[32], w1[32];
    {
        const f4* s0 = (const f4*)(Wih + (size_t)(2 * l) * II);
        const f4* s1 = (const f4*)(Wih + (size_t)(2 * l + 1) * II);
        #pragma unroll
        for (int m = 0; m < 16; ++m) {
            f4 v0 = s0[m], v1 = s1[m];
            w0[2 * m] = (f2){v0.x, v0.y}; w0[2 * m + 1] = (f2){v0.z, v0.w};
            w1[2 * m] = (f2){v1.x, v1.y}; w1[2 * m + 1] = (f2){v1.z, v1.w};
        }
    }
    const float bias0 = bih[2 * l]     + bhh[2 * l];
    const float bias1 = bih[2 * l + 1] + bhh[2 * l + 1];
    __syncthreads();

    unsigned* xpd = xp + ((size_t)(d * BB + b) * TT + (size_t)tt * 256) * (HH / 2);
    for (int ti = 0; ti < 64; ++ti) {
        const int t_loc = w * 64 + ti;
        const f4* xr = (const f4*)(xs + t_loc * II);
        f2 a0 = (f2){0, 0}, a0b = (f2){0, 0}, a1 = (f2){0, 0}, a1b = (f2){0, 0};
        #pragma unroll
        for (int m = 0; m < 16; ++m) {
            f4 v = xr[m];
            f2 lo = (f2){v.x, v.y}, hi = (f2){v.z, v.w};
            a0  += w0[2 * m] * lo;  a0b += w0[2 * m + 1] * hi;
            a1  += w1[2 * m] * lo;  a1b += w1[2 * m + 1] * hi;
        }
        float z0 = (a0.x + a0.y + a0b.x + a0b.y + bias0) * SCALE_C;
        float z1 = (a1.x + a1.y + a1b.x + a1b.y + bias1) * SCALE_C;
        xpd[(size_t)t_loc * (HH / 2) + l] = pack_h16(z0, z1);
    }
}

// =====================================================================
// Kernel 2: serial recurrence v7 — round 6's PASSING kernel (one wave
// per (b,d), no barriers, f16 weights rows 2l/2l+1 in regs, uniform u4
// h reads, 2-deep xp prefetch) with ONE targeted change:
//
//   The 16 h ds_read_b128s are hoisted into a statically-indexed hv[16]
//   burst, fenced from the dot2 cluster by sched_barrier(0). Round 6's
//   scheduler interleaved read->dot pairwise (VGPR=132 = minimal), each
//   read exposing ~70cy LDS latency -> ~1120cy/step. The fence forces
//   one pipelined burst (~170cy) and forces the RA to keep 16 u4 live.
//   __launch_bounds__(64,1) -> 512-reg budget, ~215 live, no spill.
// =====================================================================
__global__ __launch_bounds__(64, 1)
void rnn_serial7(const float* __restrict__ Whh_f, const float* __restrict__ Whh_b,
                 const unsigned* __restrict__ xp, unsigned* __restrict__ y)
{
    const int l = threadIdx.x;          // lane: owns rows 2l, 2l+1
    const int b = blockIdx.x & 63;
    const int d = blockIdx.x >> 6;
    const float* __restrict__ Whh = d ? Whh_b : Whh_f;

    __shared__ __align__(16) unsigned hb[2][HH / 2];  // f16 pairs, 256 B/buf

    // rows 2l, 2l+1 of Whh, scaled by C, f16-packed (round 6/7 pattern)
    unsigned wu0[64], wu1[64];
    {
        const f4* s0 = (const f4*)(Whh + (size_t)(2 * l) * HH);
        const f4* s1 = (const f4*)(Whh + (size_t)(2 * l + 1) * HH);
        #pragma unroll
        for (int m = 0; m < 32; ++m) {
            f4 v0 = s0[m], v1 = s1[m];
            wu0[2 * m]     = pack_h16(v0.x * SCALE_C, v0.y * SCALE_C);
            wu0[2 * m + 1] = pack_h16(v0.z * SCALE_C, v0.w * SCALE_C);
            wu1[2 * m]     = pack_h16(v1.x * SCALE_C, v1.y * SCALE_C);
            wu1[2 * m + 1] = pack_h16(v1.z * SCALE_C, v1.w * SCALE_C);
        }
    }

    hb[0][l] = 0u;   // h0 = 0

    const size_t base_pair = (size_t)(d * BB + b) * TT * (HH / 2);
    const unsigned* xpl = xp + base_pair + l;
    unsigned*       yl  = y  + base_pair + l;

    const int t0 = d ? (TT - 1) : 0;
    const int dt = d ? -1 : 1;

    // 2-deep prefetch rotation — EXACT round-6 shape (proven)
    unsigned xc = xpl[(size_t)t0 * (HH / 2)];
    unsigned xn = xpl[(size_t)(t0 + dt) * (HH / 2)];

    #pragma unroll 2
    for (int s = 0; s < TT; ++s) {
        const int cur = s & 1, nxt = cur ^ 1;

        // prefetch xp for s+2 — never waited this iteration
        unsigned xf = 0;
        if (s + 2 < TT) xf = xpl[(size_t)(t0 + dt * (s + 2)) * (HH / 2)];

        // ---- burst-load the full h vector: 16 uniform ds_read_b128 ----
        const u4* hr = (const u4*)hb[cur];
        u4 hv[16];
        #pragma unroll
        for (int m = 0; m < 16; ++m) hv[m] = hr[m];
        // Fence: reads may not sink below, dots may not hoist above.
        __builtin_amdgcn_sched_barrier(0);

        // ---- z' = C*(Whh·h + xp): 128 dot2, 8 accumulation chains ----
        float a00 = 0, a01 = 0, a02 = 0, a03 = 0;
        float a10 = 0, a11 = 0, a12 = 0, a13 = 0;
        #pragma unroll
        for (int m = 0; m < 16; ++m) {
            u4 v = hv[m];
            a00 = dot2asm(wu0[4 * m],     v.x, a00);
            a01 = dot2asm(wu0[4 * m + 1], v.y, a01);
            a02 = dot2asm(wu0[4 * m + 2], v.z, a02);
            a03 = dot2asm(wu0[4 * m + 3], v.w, a03);
            a10 = dot2asm(wu1[4 * m],     v.x, a10);
            a11 = dot2asm(wu1[4 * m + 1], v.y, a11);
            a12 = dot2asm(wu1[4 * m + 2], v.z, a12);
            a13 = dot2asm(wu1[4 * m + 3], v.w, a13);
        }
        float z0 = (a00 + a01) + (a02 + a03) + h16_lo(xc);
        float z1 = (a10 + a11) + (a12 + a13) + h16_hi(xc);

        // tanh(z) = 1 - 2/(2^{z'}+1), inf-safe
        float e0 = exp2asm(z0);
        float e1 = exp2asm(z1);
        float h0 = 1.f - __fdividef(2.f, e0 + 1.f);
        float h1 = 1.f - __fdividef(2.f, e1 + 1.f);

        const unsigned hp = pack_h16(h0, h1);
        hb[nxt][l] = hp;                              // DS in-order: no wait needed
        yl[(size_t)(t0 + dt * s) * (HH / 2)] = hp;    // streamed, never waited

        xc = xn; xn = xf;
    }
}

// =====================================================================
// Kernel 3 (verbatim from round 7, PASSED): out = Wout·[y_f;y_b] + bout
// =====================================================================
__global__ __launch_bounds__(256, 1)
void out_kernel(const unsigned* __restrict__ y, const float* __restrict__ Wout,
                const float* __restrict__ bout, float* __restrict__ out)
{
    const int blk = blockIdx.x;
    const int tt = blk & 31;
    const int b  = blk >> 5;
    const int tid = threadIdx.x;
    const int w = tid >> 6, l = tid & 63;

    __shared__ float ys[64][2 * HH];   // 64 KiB

    const unsigned* yf = y + ((size_t)(0 * BB + b) * TT + (size_t)tt * 64) * (HH / 2);
    const unsigned* yb = y + ((size_t)(1 * BB + b) * TT + (size_t)tt * 64) * (HH / 2);
    for (int i = tid; i < 64 * (HH / 2); i += 256) {
        const int t_loc = i >> 6, hp = i & 63;
        unsigned vf = yf[i], vb = yb[i];
        ys[t_loc][2 * hp]          = h16_lo(vf);
        ys[t_loc][2 * hp + 1]      = h16_hi(vf);
        ys[t_loc][HH + 2 * hp]     = h16_lo(vb);
        ys[t_loc][HH + 2 * hp + 1] = h16_hi(vb);
    }

    const int o  = 32 * (w & 1) + (l >> 1);
    const int ks = l & 1;
    f2 wv[64];
    {
        const f4* s = (const f4*)(Wout + (size_t)o * (2 * HH) + (size_t)ks * HH);
        #pragma unroll
        for (int m = 0; m < 32; ++m) {
            f4 v = s[m];
            wv[2 * m] = (f2){v.x, v.y}; wv[2 * m + 1] = (f2){v.z, v.w};
        }
    }
    const float bo = bout[o];
    __syncthreads();

    for (int i = 0; i < 32; ++i) {
        const int t_loc = 2 * i + (w >> 1);
        const f4* yr = (const f4*)(&ys[t_loc][ks * HH]);
        f2 acc = (f2){0, 0}, accb = (f2){0, 0};
        #pragma unroll
        for (int m = 0; m < 32; ++m) {
            f4 v = yr[m];
            acc  += wv[2 * m]     * (f2){v.x, v.y};
            accb += wv[2 * m + 1] * (f2){v.z, v.w};
        }
        float r = acc.x + acc.y + accb.x + accb.y;
        r += __shfl_xor(r, 1);
        if (ks == 0)
            out[((size_t)b * TT + (size_t)tt * 64 + t_loc) * OO + o] = r + bo;
    }
}

// =====================================================================
// Fallback (ws too small): known-good fused kernel from round 3 (1689 us).
// =====================================================================
__global__ __launch_bounds__(256, 1)
void birnn_fused(const float* __restrict__ x,
                 const float* __restrict__ Wih_f, const float* __restrict__ Whh_f,
                 const float* __restrict__ bih_f, const float* __restrict__ bhh_f,
                 const float* __restrict__ Wih_b, const float* __restrict__ Whh_b,
                 const float* __restrict__ bih_b, const float* __restrict__ bhh_b,
                 const float* __restrict__ Wout, const float* __restrict__ bout,
                 float* __restrict__ out)
{
    const int tid = threadIdx.x;
    const int b   = blockIdx.x & (BB - 1);
    const int d   = blockIdx.x >> 6;
    const float* __restrict__ Wih = d ? Wih_b : Wih_f;
    const float* __restrict__ Whh = d ? Whh_b : Whh_f;
    const float* __restrict__ bih = d ? bih_b : bih_f;
    const float* __restrict__ bhh = d ? bhh_b : bhh_f;
    const int j = tid >> 1, p = tid & 1, o = tid >> 2, os = tid & 3;
    __shared__ float hbuf[2][HH];
    __shared__ float xbuf[2][II];
    f2 whh[32], wih[16], wo[16];
    {
        const f4* s4 = (const f4*)(Whh + (size_t)j * HH + p * 64);
        #pragma unroll
        for (int m = 0; m < 16; ++m) { f4 v = s4[m]; whh[2*m]=(f2){v.x,v.y}; whh[2*m+1]=(f2){v.z,v.w}; }
    }
    {
        const f4* s4 = (const f4*)(Wih + (size_t)j * II + p * 32);
        #pragma unroll
        for (int m = 0; m < 8; ++m) { f4 v = s4[m]; wih[2*m]=(f2){v.x,v.y}; wih[2*m+1]=(f2){v.z,v.w}; }
    }
    {
        const f4* s4 = (const f4*)(Wout + (size_t)o * (2*HH) + d*HH + os*32);
        #pragma unroll
        for (int m = 0; m < 8; ++m) { f4 v = s4[m]; wo[2*m]=(f2){v.x,v.y}; wo[2*m+1]=(f2){v.z,v.w}; }
    }
    const float bj = bih[j] + bhh[j];
    const float bo = d ? 0.f : bout[o];
    const float* __restrict__ xb   = x   + (size_t)b * TT * II;
    float*       __restrict__ outb = out + (size_t)b * TT * OO;
    const int t0 = d ? (TT - 1) : 0;
    const int dt = d ? -1 : 1;
    float xpre = 0.f;
    if (tid < II) {
        xbuf[0][tid] = xb[(size_t)t0 * II + tid];
        xpre = xb[(size_t)(t0 + dt) * II + tid];
    }
    if (tid < HH) hbuf[0][tid] = 0.f;
    __syncthreads();
    #pragma unroll 2
    for (int s = 0; s < TT; ++s) {
        const int cur = s & 1, nxt = cur ^ 1;
        if (s > 0) {
            const f4* hv4 = (const f4*)(&hbuf[cur][os * 32]);
            f2 acc = (f2){0.f, 0.f};
            #pragma unroll
            for (int m = 0; m < 8; ++m) { f4 h4 = hv4[m]; acc += wo[2*m]*(f2){h4.x,h4.y}; acc += wo[2*m+1]*(f2){h4.z,h4.w}; }
            float v = acc.x + acc.y;
            v += __shfl_xor(v, 1); v += __shfl_xor(v, 2);
            if (os == 0) atomicAdd(&outb[(size_t)(t0 + dt*(s-1)) * OO + o], v + bo);
        }
        {
            const f4* hv4 = (const f4*)(&hbuf[cur][p * 64]);
            const f4* xv4 = (const f4*)(&xbuf[cur][p * 32]);
            f2 acc = (f2){0.f, 0.f};
            #pragma unroll
            for (int m = 0; m < 16; ++m) { f4 h4 = hv4[m]; acc += whh[2*m]*(f2){h4.x,h4.y}; acc += whh[2*m+1]*(f2){h4.z,h4.w}; }
            #pragma unroll
            for (int m = 0; m < 8; ++m) { f4 x4 = xv4[m]; acc += wih[2*m]*(f2){x4.x,x4.y}; acc += wih[2*m+1]*(f2){x4.z,x4.w}; }
            float z = acc.x + acc.y;
            z += __shfl_xor(z, 1);
            z += bj;
            float e = __expf(2.f * z);
            float h = 1.f - __fdividef(2.f, e + 1.f);
            if (p == 0) hbuf[nxt][j] = h;
        }
        if (tid < II) {
            xbuf[nxt][tid] = xpre;
            if (s + 2 < TT) xpre = xb[(size_t)(t0 + dt*(s+2)) * II + tid];
        }
        __syncthreads();
    }
    {
        const f4* hv4 = (const f4*)(&hbuf[TT & 1][os * 32]);
        f2 acc = (f2){0.f, 0.f};
        #pragma unroll
        for (int m = 0; m < 8; ++m) { f4 h4 = hv4[m]; acc += wo[2*m]*(f2){h4.x,h4.y}; acc += wo[2*m+1]*(f2){h4.z,h4.w}; }
        float v = acc.x + acc.y;
        v += __shfl_xor(v, 1); v += __shfl_xor(v, 2);
        if (os == 0) atomicAdd(&outb[(size_t)(t0 + dt*(TT-1)) * OO + o], v + bo);
    }
}

extern "C" void kernel_launch(void* const* d_in, const int* in_sizes, int n_in,
                              void* d_out, int out_size, void* d_ws, size_t ws_size,
                              hipStream_t stream) {
    const float* x     = (const float*)d_in[0];
    const float* Wih_f = (const float*)d_in[1];
    const float* Whh_f = (const float*)d_in[2];
    const float* bih_f = (const float*)d_in[3];
    const float* bhh_f = (const float*)d_in[4];
    const float* Wih_b = (const float*)d_in[5];
    const float* Whh_b = (const float*)d_in[6];
    const float* bih_b = (const float*)d_in[7];
    const float* bhh_b = (const float*)d_in[8];
    const float* Wout  = (const float*)d_in[9];
    const float* bout  = (const float*)d_in[10];
    float* out = (float*)d_out;

    const size_t xp_bytes = (size_t)2 * BB * TT * (HH / 2) * 4;  // 64 MiB (f16 pairs)
    const size_t y_bytes  = xp_bytes;                             // 64 MiB
    if (ws_size >= xp_bytes + y_bytes) {
        unsigned* xp_ws = (unsigned*)d_ws;
        unsigned* y_ws  = (unsigned*)((char*)d_ws + xp_bytes);
        xp_kernel<<<dim3(1024), dim3(256), 0, stream>>>(
            x, Wih_f, bih_f, bhh_f, Wih_b, bih_b, bhh_b, xp_ws);
        rnn_serial7<<<dim3(2 * BB), dim3(64), 0, stream>>>(
            Whh_f, Whh_b, xp_ws, y_ws);
        out_kernel<<<dim3(2048), dim3(256), 0, stream>>>(y_ws, Wout, bout, out);
    } else {
        hipMemsetAsync(d_out, 0, (size_t)out_size * sizeof(float), stream);
        birnn_fused<<<dim3(2 * BB), dim3(256), 0, stream>>>(
            x, Wih_f, Whh_f, bih_f, bhh_f,
            Wih_b, Whh_b, bih_b, bhh_b, Wout, bout, out);
    }
}